// Round 1
// baseline (474.701 us; speedup 1.0000x reference)
//
#include <hip/hip_runtime.h>
#include <stdint.h>

// DSA sparse attention, MI355X. T=512 tok, H=128 heads, K=512 selected keys,
// C=576 (512 lora + 64 rope), S=8192 cache rows.
// Pipeline: kv->bf16, rope copy (SCALE folded), q_lat GEMM, scores GEMM,
// row softmax, attn GEMM, out GEMM. All GEMMs: 128x128 tile, BK=32,
// 4 waves x (4x4 of 16x16x32 bf16 MFMA), verified m90/m92 layout:
// A[m=lane&15][k=quad*8+j], B[n=lane&15][k=quad*8+j], D col=lane&15 row=quad*4+reg.

#define SCALE 0.041666666666666664f  // (512+64)^-0.5

typedef __bf16 bf16x8 __attribute__((ext_vector_type(8)));
typedef float floatx4 __attribute__((ext_vector_type(4)));

static __device__ __forceinline__ unsigned short f2bf(float f) {
  unsigned int u = __builtin_bit_cast(unsigned int, f);
  u += 0x7FFF + ((u >> 16) & 1);  // RNE
  return (unsigned short)(u >> 16);
}
static __device__ __forceinline__ float bf2f(unsigned short h) {
  unsigned int u = ((unsigned int)h) << 16;
  return __builtin_bit_cast(float, u);
}
static __device__ __forceinline__ unsigned int pack2(float lo, float hi) {
  return (unsigned int)f2bf(lo) | ((unsigned int)f2bf(hi) << 16);
}
// stage 8 fp32 -> 8 bf16 into LDS (16B aligned)
static __device__ __forceinline__ void stage8_f32(const float* __restrict__ src,
                                                  unsigned short* dst) {
  const float4* s4 = reinterpret_cast<const float4*>(src);
  float4 v0 = s4[0], v1 = s4[1];
  uint4 o;
  o.x = pack2(v0.x, v0.y); o.y = pack2(v0.z, v0.w);
  o.z = pack2(v1.x, v1.y); o.w = pack2(v1.z, v1.w);
  *reinterpret_cast<uint4*>(dst) = o;
}
// stage 8 bf16 -> LDS (plain 16B copy)
static __device__ __forceinline__ void stage8_bf(const unsigned short* __restrict__ src,
                                                 unsigned short* dst) {
  *reinterpret_cast<uint4*>(dst) = *reinterpret_cast<const uint4*>(src);
}

static __device__ __forceinline__ void mfma_4x4(const unsigned short* As,
                                                const unsigned short* Bs,
                                                int wm, int wn, int l15, int quad,
                                                floatx4 acc[4][4]) {
  bf16x8 af[4], bfr[4];
#pragma unroll
  for (int i = 0; i < 4; ++i)
    af[i] = *reinterpret_cast<const bf16x8*>(&As[(wm + i * 16 + l15) * 32 + quad * 8]);
#pragma unroll
  for (int j = 0; j < 4; ++j)
    bfr[j] = *reinterpret_cast<const bf16x8*>(&Bs[(wn + j * 16 + l15) * 32 + quad * 8]);
#pragma unroll
  for (int i = 0; i < 4; ++i)
#pragma unroll
    for (int j = 0; j < 4; ++j)
      acc[i][j] = __builtin_amdgcn_mfma_f32_16x16x32_bf16(af[i], bfr[j], acc[i][j], 0, 0, 0);
}

// ---------------- K0a: kv_cache fp32 -> bf16 ----------------
__global__ void kv_convert(const float* __restrict__ kv, unsigned short* __restrict__ kvb) {
  int i = blockIdx.x * 256 + threadIdx.x;  // per 4 elems, grid sized exactly
  float4 v = reinterpret_cast<const float4*>(kv)[i];
  ushort4 o;
  o.x = f2bf(v.x); o.y = f2bf(v.y); o.z = f2bf(v.z); o.w = f2bf(v.w);
  reinterpret_cast<ushort4*>(kvb)[i] = o;
}

// ---------------- K0b: q_rope * SCALE -> q_concat[..., 512:576] ----------------
__global__ void rope_copy(const float* __restrict__ q, unsigned short* __restrict__ qc) {
  int i = blockIdx.x * 256 + threadIdx.x;  // 512*128*64 total
  int r = i & 63;
  int th = i >> 6;  // t*128 + h
  qc[(size_t)th * 576 + 512 + r] = f2bf(q[(size_t)th * 192 + 128 + r] * SCALE);
}

// ---------------- K1: q_lat = per-head (T x 128) @ (512 x 128)^T, * SCALE ----------------
__global__ __launch_bounds__(256) void qlat_gemm(const float* __restrict__ q,
                                                 const float* __restrict__ kb,
                                                 unsigned short* __restrict__ qc) {
  const int h = blockIdx.y;
  const int tm = (blockIdx.x & 3) * 128;   // token tile
  const int tn = (blockIdx.x >> 2) * 128;  // lora-dim tile
  __shared__ __align__(16) unsigned short As[128 * 32];
  __shared__ __align__(16) unsigned short Bs[128 * 32];
  const int tid = threadIdx.x;
  const int lane = tid & 63, wave = tid >> 6;
  const int wm = (wave & 1) * 64, wn = (wave >> 1) * 64;
  const int l15 = lane & 15, quad = lane >> 4;
  const int r0 = tid >> 2, cg = tid & 3;  // chunk row, col-group(8); +256 chunk = row+64
  const float* a0 = q + ((size_t)(tm + r0) * 128 + h) * 192 + cg * 8;
  const float* a1 = q + ((size_t)(tm + r0 + 64) * 128 + h) * 192 + cg * 8;
  const float* b0 = kb + ((size_t)h * 512 + tn + r0) * 128 + cg * 8;
  const float* b1 = b0 + (size_t)64 * 128;
  floatx4 acc[4][4] = {};
  for (int ks = 0; ks < 4; ++ks) {  // contraction 128 = 4*32
    stage8_f32(a0 + ks * 32, &As[r0 * 32 + cg * 8]);
    stage8_f32(a1 + ks * 32, &As[(r0 + 64) * 32 + cg * 8]);
    stage8_f32(b0 + ks * 32, &Bs[r0 * 32 + cg * 8]);
    stage8_f32(b1 + ks * 32, &Bs[(r0 + 64) * 32 + cg * 8]);
    __syncthreads();
    mfma_4x4(As, Bs, wm, wn, l15, quad, acc);
    __syncthreads();
  }
#pragma unroll
  for (int i = 0; i < 4; ++i) {
    const int row = wm + i * 16 + quad * 4;  // token-local
#pragma unroll
    for (int j = 0; j < 4; ++j) {
      const int col = wn + j * 16 + l15;  // lora-dim-local
#pragma unroll
      for (int r = 0; r < 4; ++r) {
        const int t = tm + row + r;
        qc[((size_t)t * 128 + h) * 576 + tn + col] = f2bf(acc[i][j][r] * SCALE);
      }
    }
  }
}

// ---------------- K2: scores (128h x 128key tile) = Qc @ KVsel^T ----------------
__global__ __launch_bounds__(256) void scores_gemm(const unsigned short* __restrict__ qc,
                                                   const unsigned short* __restrict__ kvb,
                                                   const int* __restrict__ topk,
                                                   unsigned short* __restrict__ P) {
  const int t = blockIdx.y;
  const int tn = blockIdx.x * 128;  // key tile
  __shared__ __align__(16) unsigned short As[128 * 32];
  __shared__ __align__(16) unsigned short Bs[128 * 32];
  const int tid = threadIdx.x;
  const int lane = tid & 63, wave = tid >> 6;
  const int wm = (wave & 1) * 64, wn = (wave >> 1) * 64;
  const int l15 = lane & 15, quad = lane >> 4;
  const int r0 = tid >> 2, cg = tid & 3;
  const unsigned short* a0 = qc + ((size_t)t * 128 + r0) * 576 + cg * 8;
  const unsigned short* a1 = a0 + (size_t)64 * 576;
  const int idx0 = topk[t * 512 + tn + r0];
  const int idx1 = topk[t * 512 + tn + r0 + 64];
  const unsigned short* b0 = kvb + (size_t)idx0 * 576 + cg * 8;
  const unsigned short* b1 = kvb + (size_t)idx1 * 576 + cg * 8;
  floatx4 acc[4][4] = {};
  for (int ks = 0; ks < 18; ++ks) {  // contraction 576 = 18*32
    stage8_bf(a0 + ks * 32, &As[r0 * 32 + cg * 8]);
    stage8_bf(a1 + ks * 32, &As[(r0 + 64) * 32 + cg * 8]);
    stage8_bf(b0 + ks * 32, &Bs[r0 * 32 + cg * 8]);
    stage8_bf(b1 + ks * 32, &Bs[(r0 + 64) * 32 + cg * 8]);
    __syncthreads();
    mfma_4x4(As, Bs, wm, wn, l15, quad, acc);
    __syncthreads();
  }
#pragma unroll
  for (int i = 0; i < 4; ++i) {
    const int row = wm + i * 16 + quad * 4;  // head
#pragma unroll
    for (int j = 0; j < 4; ++j) {
      const int col = tn + wn + j * 16 + l15;  // key
#pragma unroll
      for (int r = 0; r < 4; ++r)
        P[((size_t)t * 128 + row + r) * 512 + col] = f2bf(acc[i][j][r]);
    }
  }
}

// ---------------- K3: in-place softmax over rows of 512 (one wave per row) ----------------
__global__ __launch_bounds__(256) void softmax_rows(unsigned short* __restrict__ P) {
  const int row = blockIdx.x * 4 + (threadIdx.x >> 6);
  const int lane = threadIdx.x & 63;
  unsigned short* rp = P + (size_t)row * 512 + lane * 8;
  uint4 raw = *reinterpret_cast<const uint4*>(rp);
  unsigned int w[4] = {raw.x, raw.y, raw.z, raw.w};
  float f[8];
  float mx = -1e30f;
#pragma unroll
  for (int i = 0; i < 8; ++i) {
    f[i] = bf2f((unsigned short)((w[i >> 1] >> ((i & 1) * 16)) & 0xFFFF));
    mx = fmaxf(mx, f[i]);
  }
#pragma unroll
  for (int off = 32; off; off >>= 1) mx = fmaxf(mx, __shfl_xor(mx, off, 64));
  float s = 0.f;
#pragma unroll
  for (int i = 0; i < 8; ++i) { f[i] = __expf(f[i] - mx); s += f[i]; }
#pragma unroll
  for (int off = 32; off; off >>= 1) s += __shfl_xor(s, off, 64);
  const float inv = 1.0f / s;
  uint4 o;
  o.x = pack2(f[0] * inv, f[1] * inv);
  o.y = pack2(f[2] * inv, f[3] * inv);
  o.z = pack2(f[4] * inv, f[5] * inv);
  o.w = pack2(f[6] * inv, f[7] * inv);
  *reinterpret_cast<uint4*>(rp) = o;
}

// ---------------- K4: attn_lat (128h x 128c tile) = P @ KVsel[:, :512] ----------------
// contraction = keys (512). B staged transposed into LDS: Bs[c_local][key_local].
__global__ __launch_bounds__(256) void attn_gemm(const unsigned short* __restrict__ P,
                                                 const unsigned short* __restrict__ kvb,
                                                 const int* __restrict__ topk,
                                                 unsigned short* __restrict__ alat) {
  const int t = blockIdx.y;
  const int tn = blockIdx.x * 128;  // c-dim tile
  __shared__ __align__(16) unsigned short As[128 * 32];
  __shared__ __align__(16) unsigned short Bs[128 * 32];
  const int tid = threadIdx.x;
  const int lane = tid & 63, wave = tid >> 6;
  const int wm = (wave & 1) * 64, wn = (wave >> 1) * 64;
  const int l15 = lane & 15, quad = lane >> 4;
  const int r0 = tid >> 2, cg = tid & 3;
  const unsigned short* a0 = P + ((size_t)t * 128 + r0) * 512 + cg * 8;
  const unsigned short* a1 = a0 + (size_t)64 * 512;
  const int keyl = tid >> 4;  // 0..15 (and +16 for second chunk)
  const int cgB = tid & 15;   // col-group of 8 c's
  const int* tkrow = topk + t * 512;
  floatx4 acc[4][4] = {};
  for (int ks = 0; ks < 16; ++ks) {  // contraction 512 keys = 16*32
    stage8_bf(a0 + ks * 32, &As[r0 * 32 + cg * 8]);
    stage8_bf(a1 + ks * 32, &As[(r0 + 64) * 32 + cg * 8]);
#pragma unroll
    for (int half = 0; half < 2; ++half) {
      const int kl = keyl + half * 16;
      const int idx = tkrow[ks * 32 + kl];
      uint4 v = *reinterpret_cast<const uint4*>(kvb + (size_t)idx * 576 + tn + cgB * 8);
      unsigned int w[4] = {v.x, v.y, v.z, v.w};
#pragma unroll
      for (int qq = 0; qq < 8; ++qq)
        Bs[(cgB * 8 + qq) * 32 + kl] =
            (unsigned short)((w[qq >> 1] >> ((qq & 1) * 16)) & 0xFFFF);
    }
    __syncthreads();
    mfma_4x4(As, Bs, wm, wn, l15, quad, acc);
    __syncthreads();
  }
  // write attn_lat in (H, T, 512) layout for K5's contiguous A reads
#pragma unroll
  for (int i = 0; i < 4; ++i) {
    const int row = wm + i * 16 + quad * 4;  // head
#pragma unroll
    for (int j = 0; j < 4; ++j) {
      const int col = tn + wn + j * 16 + l15;  // c
#pragma unroll
      for (int r = 0; r < 4; ++r)
        alat[((size_t)(row + r) * 512 + t) * 512 + col] = f2bf(acc[i][j][r]);
    }
  }
}

// ---------------- K5: out (128t x 128v tile) = attn_lat[h] @ v_b[h]^T ----------------
__global__ __launch_bounds__(256) void out_gemm(const unsigned short* __restrict__ alat,
                                                const float* __restrict__ vb,
                                                float* __restrict__ out) {
  const int h = blockIdx.y;
  const int tm = blockIdx.x * 128;  // token tile
  __shared__ __align__(16) unsigned short As[128 * 32];
  __shared__ __align__(16) unsigned short Bs[128 * 32];
  const int tid = threadIdx.x;
  const int lane = tid & 63, wave = tid >> 6;
  const int wm = (wave & 1) * 64, wn = (wave >> 1) * 64;
  const int l15 = lane & 15, quad = lane >> 4;
  const int r0 = tid >> 2, cg = tid & 3;
  const unsigned short* a0 = alat + ((size_t)h * 512 + tm + r0) * 512 + cg * 8;
  const unsigned short* a1 = a0 + (size_t)64 * 512;
  const float* b0 = vb + ((size_t)h * 128 + r0) * 512 + cg * 8;
  const float* b1 = b0 + (size_t)64 * 512;
  floatx4 acc[4][4] = {};
  for (int ks = 0; ks < 16; ++ks) {  // contraction 512 = 16*32
    stage8_bf(a0 + ks * 32, &As[r0 * 32 + cg * 8]);
    stage8_bf(a1 + ks * 32, &As[(r0 + 64) * 32 + cg * 8]);
    stage8_f32(b0 + ks * 32, &Bs[r0 * 32 + cg * 8]);
    stage8_f32(b1 + ks * 32, &Bs[(r0 + 64) * 32 + cg * 8]);
    __syncthreads();
    mfma_4x4(As, Bs, wm, wn, l15, quad, acc);
    __syncthreads();
  }
#pragma unroll
  for (int i = 0; i < 4; ++i) {
    const int row = wm + i * 16 + quad * 4;  // token-local
#pragma unroll
    for (int j = 0; j < 4; ++j) {
      const int col = wn + j * 16 + l15;  // v
#pragma unroll
      for (int r = 0; r < 4; ++r) {
        const int t = tm + row + r;
        out[((size_t)t * 128 + h) * 128 + col] = acc[i][j][r];
      }
    }
  }
}

extern "C" void kernel_launch(void* const* d_in, const int* in_sizes, int n_in,
                              void* d_out, int out_size, void* d_ws, size_t ws_size,
                              hipStream_t stream) {
  const float* q = (const float*)d_in[0];         // (512,128,192)
  const float* kv = (const float*)d_in[1];        // (8192,576)
  const int* topk = (const int*)d_in[2];          // (512,512)
  const float* kb = (const float*)d_in[3];        // (128,512,128)
  const float* vb = (const float*)d_in[4];        // (128,128,512)
  float* out = (float*)d_out;                     // (512,128,128)

  char* ws = (char*)d_ws;
  unsigned short* kvb = (unsigned short*)ws;                              // 9,437,184 B
  unsigned short* qc = (unsigned short*)(ws + 9437184);                   // 75,497,472 B
  unsigned short* alat = qc;                                              // reuse (67,108,864 B)
  unsigned short* P = (unsigned short*)(ws + 9437184 + 75497472);         // 67,108,864 B
  // total ws need: 152,043,520 B

  kv_convert<<<dim3(4608), dim3(256), 0, stream>>>(kv, kvb);
  rope_copy<<<dim3(16384), dim3(256), 0, stream>>>(q, qc);
  qlat_gemm<<<dim3(16, 128), dim3(256), 0, stream>>>(q, kb, qc);
  scores_gemm<<<dim3(4, 512), dim3(256), 0, stream>>>(qc, kvb, topk, P);
  softmax_rows<<<dim3(16384), dim3(256), 0, stream>>>(P);
  attn_gemm<<<dim3(4, 512), dim3(256), 0, stream>>>(P, kvb, topk, alat);
  out_gemm<<<dim3(4, 128), dim3(256), 0, stream>>>(alat, vb, out);
}

// Round 2
// 402.749 us; speedup vs baseline: 1.1787x; 1.1787x over previous
//
#include <hip/hip_runtime.h>
#include <stdint.h>

// DSA sparse attention, MI355X. T=512 tok, H=128 heads, K=512 selected keys,
// C=576 (512 lora + 64 rope), S=8192 cache rows.
// Pipeline: kv->bf16, rope copy (SCALE folded), q_lat GEMM, scores GEMM,
// row softmax, attn GEMM, out GEMM. All GEMMs: 128x128 tile, BK=32,
// 4 waves x (4x4 of 16x16x32 bf16 MFMA), verified m90/m92 layout:
// A[m=lane&15][k=quad*8+j], B[n=lane&15][k=quad*8+j], D col=lane&15 row=quad*4+reg.
//
// R1 -> R2: attn_gemm had SQ_LDS_BANK_CONFLICT=6.7e7 (~109us/CU of serialization)
// from a scalar transposed store (2 banks across 64 lanes). Replaced with
// coalesced stage [key][c] + conflict-free transpose into Bs with row stride
// padded to 40 shorts (banks (20c+4kg)%32 cover all 32 banks per 8 rows).

#define SCALE 0.041666666666666664f  // (512+64)^-0.5

typedef __bf16 bf16x8 __attribute__((ext_vector_type(8)));
typedef float floatx4 __attribute__((ext_vector_type(4)));

static __device__ __forceinline__ unsigned short f2bf(float f) {
  unsigned int u = __builtin_bit_cast(unsigned int, f);
  u += 0x7FFF + ((u >> 16) & 1);  // RNE
  return (unsigned short)(u >> 16);
}
static __device__ __forceinline__ float bf2f(unsigned short h) {
  unsigned int u = ((unsigned int)h) << 16;
  return __builtin_bit_cast(float, u);
}
static __device__ __forceinline__ unsigned int pack2(float lo, float hi) {
  return (unsigned int)f2bf(lo) | ((unsigned int)f2bf(hi) << 16);
}
// stage 8 fp32 -> 8 bf16 into LDS (16B aligned)
static __device__ __forceinline__ void stage8_f32(const float* __restrict__ src,
                                                  unsigned short* dst) {
  const float4* s4 = reinterpret_cast<const float4*>(src);
  float4 v0 = s4[0], v1 = s4[1];
  uint4 o;
  o.x = pack2(v0.x, v0.y); o.y = pack2(v0.z, v0.w);
  o.z = pack2(v1.x, v1.y); o.w = pack2(v1.z, v1.w);
  *reinterpret_cast<uint4*>(dst) = o;
}
// stage 8 bf16 -> LDS (plain 16B copy)
static __device__ __forceinline__ void stage8_bf(const unsigned short* __restrict__ src,
                                                 unsigned short* dst) {
  *reinterpret_cast<uint4*>(dst) = *reinterpret_cast<const uint4*>(src);
}

static __device__ __forceinline__ void mfma_4x4_s(const unsigned short* As,
                                                  const unsigned short* Bs,
                                                  int wm, int wn, int l15, int quad,
                                                  int bstride, floatx4 acc[4][4]) {
  bf16x8 af[4], bfr[4];
#pragma unroll
  for (int i = 0; i < 4; ++i)
    af[i] = *reinterpret_cast<const bf16x8*>(&As[(wm + i * 16 + l15) * 32 + quad * 8]);
#pragma unroll
  for (int j = 0; j < 4; ++j)
    bfr[j] = *reinterpret_cast<const bf16x8*>(&Bs[(wn + j * 16 + l15) * bstride + quad * 8]);
#pragma unroll
  for (int i = 0; i < 4; ++i)
#pragma unroll
    for (int j = 0; j < 4; ++j)
      acc[i][j] = __builtin_amdgcn_mfma_f32_16x16x32_bf16(af[i], bfr[j], acc[i][j], 0, 0, 0);
}
static __device__ __forceinline__ void mfma_4x4(const unsigned short* As,
                                                const unsigned short* Bs,
                                                int wm, int wn, int l15, int quad,
                                                floatx4 acc[4][4]) {
  mfma_4x4_s(As, Bs, wm, wn, l15, quad, 32, acc);
}

// ---------------- K0a: kv_cache fp32 -> bf16 ----------------
__global__ void kv_convert(const float* __restrict__ kv, unsigned short* __restrict__ kvb) {
  int i = blockIdx.x * 256 + threadIdx.x;  // per 4 elems, grid sized exactly
  float4 v = reinterpret_cast<const float4*>(kv)[i];
  ushort4 o;
  o.x = f2bf(v.x); o.y = f2bf(v.y); o.z = f2bf(v.z); o.w = f2bf(v.w);
  reinterpret_cast<ushort4*>(kvb)[i] = o;
}

// ---------------- K0b: q_rope * SCALE -> q_concat[..., 512:576] ----------------
__global__ void rope_copy(const float* __restrict__ q, unsigned short* __restrict__ qc) {
  int i = blockIdx.x * 256 + threadIdx.x;  // 512*128*64 total
  int r = i & 63;
  int th = i >> 6;  // t*128 + h
  qc[(size_t)th * 576 + 512 + r] = f2bf(q[(size_t)th * 192 + 128 + r] * SCALE);
}

// ---------------- K1: q_lat = per-head (T x 128) @ (512 x 128)^T, * SCALE ----------------
__global__ __launch_bounds__(256) void qlat_gemm(const float* __restrict__ q,
                                                 const float* __restrict__ kb,
                                                 unsigned short* __restrict__ qc) {
  const int h = blockIdx.y;
  const int tm = (blockIdx.x & 3) * 128;   // token tile
  const int tn = (blockIdx.x >> 2) * 128;  // lora-dim tile
  __shared__ __align__(16) unsigned short As[128 * 32];
  __shared__ __align__(16) unsigned short Bs[128 * 32];
  const int tid = threadIdx.x;
  const int lane = tid & 63, wave = tid >> 6;
  const int wm = (wave & 1) * 64, wn = (wave >> 1) * 64;
  const int l15 = lane & 15, quad = lane >> 4;
  const int r0 = tid >> 2, cg = tid & 3;  // chunk row, col-group(8); +256 chunk = row+64
  const float* a0 = q + ((size_t)(tm + r0) * 128 + h) * 192 + cg * 8;
  const float* a1 = q + ((size_t)(tm + r0 + 64) * 128 + h) * 192 + cg * 8;
  const float* b0 = kb + ((size_t)h * 512 + tn + r0) * 128 + cg * 8;
  const float* b1 = b0 + (size_t)64 * 128;
  floatx4 acc[4][4] = {};
  for (int ks = 0; ks < 4; ++ks) {  // contraction 128 = 4*32
    stage8_f32(a0 + ks * 32, &As[r0 * 32 + cg * 8]);
    stage8_f32(a1 + ks * 32, &As[(r0 + 64) * 32 + cg * 8]);
    stage8_f32(b0 + ks * 32, &Bs[r0 * 32 + cg * 8]);
    stage8_f32(b1 + ks * 32, &Bs[(r0 + 64) * 32 + cg * 8]);
    __syncthreads();
    mfma_4x4(As, Bs, wm, wn, l15, quad, acc);
    __syncthreads();
  }
#pragma unroll
  for (int i = 0; i < 4; ++i) {
    const int row = wm + i * 16 + quad * 4;  // token-local
#pragma unroll
    for (int j = 0; j < 4; ++j) {
      const int col = wn + j * 16 + l15;  // lora-dim-local
#pragma unroll
      for (int r = 0; r < 4; ++r) {
        const int t = tm + row + r;
        qc[((size_t)t * 128 + h) * 576 + tn + col] = f2bf(acc[i][j][r] * SCALE);
      }
    }
  }
}

// ---------------- K2: scores (128h x 128key tile) = Qc @ KVsel^T ----------------
__global__ __launch_bounds__(256) void scores_gemm(const unsigned short* __restrict__ qc,
                                                   const unsigned short* __restrict__ kvb,
                                                   const int* __restrict__ topk,
                                                   unsigned short* __restrict__ P) {
  const int t = blockIdx.y;
  const int tn = blockIdx.x * 128;  // key tile
  __shared__ __align__(16) unsigned short As[128 * 32];
  __shared__ __align__(16) unsigned short Bs[128 * 32];
  const int tid = threadIdx.x;
  const int lane = tid & 63, wave = tid >> 6;
  const int wm = (wave & 1) * 64, wn = (wave >> 1) * 64;
  const int l15 = lane & 15, quad = lane >> 4;
  const int r0 = tid >> 2, cg = tid & 3;
  const unsigned short* a0 = qc + ((size_t)t * 128 + r0) * 576 + cg * 8;
  const unsigned short* a1 = a0 + (size_t)64 * 576;
  const int idx0 = topk[t * 512 + tn + r0];
  const int idx1 = topk[t * 512 + tn + r0 + 64];
  const unsigned short* b0 = kvb + (size_t)idx0 * 576 + cg * 8;
  const unsigned short* b1 = kvb + (size_t)idx1 * 576 + cg * 8;
  floatx4 acc[4][4] = {};
  for (int ks = 0; ks < 18; ++ks) {  // contraction 576 = 18*32
    stage8_bf(a0 + ks * 32, &As[r0 * 32 + cg * 8]);
    stage8_bf(a1 + ks * 32, &As[(r0 + 64) * 32 + cg * 8]);
    stage8_bf(b0 + ks * 32, &Bs[r0 * 32 + cg * 8]);
    stage8_bf(b1 + ks * 32, &Bs[(r0 + 64) * 32 + cg * 8]);
    __syncthreads();
    mfma_4x4(As, Bs, wm, wn, l15, quad, acc);
    __syncthreads();
  }
#pragma unroll
  for (int i = 0; i < 4; ++i) {
    const int row = wm + i * 16 + quad * 4;  // head
#pragma unroll
    for (int j = 0; j < 4; ++j) {
      const int col = tn + wn + j * 16 + l15;  // key
#pragma unroll
      for (int r = 0; r < 4; ++r)
        P[((size_t)t * 128 + row + r) * 512 + col] = f2bf(acc[i][j][r]);
    }
  }
}

// ---------------- K3: in-place softmax over rows of 512 (one wave per row) ----------------
__global__ __launch_bounds__(256) void softmax_rows(unsigned short* __restrict__ P) {
  const int row = blockIdx.x * 4 + (threadIdx.x >> 6);
  const int lane = threadIdx.x & 63;
  unsigned short* rp = P + (size_t)row * 512 + lane * 8;
  uint4 raw = *reinterpret_cast<const uint4*>(rp);
  unsigned int w[4] = {raw.x, raw.y, raw.z, raw.w};
  float f[8];
  float mx = -1e30f;
#pragma unroll
  for (int i = 0; i < 8; ++i) {
    f[i] = bf2f((unsigned short)((w[i >> 1] >> ((i & 1) * 16)) & 0xFFFF));
    mx = fmaxf(mx, f[i]);
  }
#pragma unroll
  for (int off = 32; off; off >>= 1) mx = fmaxf(mx, __shfl_xor(mx, off, 64));
  float s = 0.f;
#pragma unroll
  for (int i = 0; i < 8; ++i) { f[i] = __expf(f[i] - mx); s += f[i]; }
#pragma unroll
  for (int off = 32; off; off >>= 1) s += __shfl_xor(s, off, 64);
  const float inv = 1.0f / s;
  uint4 o;
  o.x = pack2(f[0] * inv, f[1] * inv);
  o.y = pack2(f[2] * inv, f[3] * inv);
  o.z = pack2(f[4] * inv, f[5] * inv);
  o.w = pack2(f[6] * inv, f[7] * inv);
  *reinterpret_cast<uint4*>(rp) = o;
}

// ---------------- K4: attn_lat (128h x 128c tile) = P @ KVsel[:, :512] ----------------
// contraction = keys (512). Conflict-free transpose:
//   St[32 key][128 c]  <- coalesced uint4 gather from kvb
//   Bs[128 c][32 key]  <- transpose, row stride 40 shorts (80B) so both the
//                         b128 writes and the b-fragment reads spread over all
//                         32 banks ((20c+4q)%32 covers 0..31 per 8 rows).
#define BSTRIDE 40
__global__ __launch_bounds__(256) void attn_gemm(const unsigned short* __restrict__ P,
                                                 const unsigned short* __restrict__ kvb,
                                                 const int* __restrict__ topk,
                                                 unsigned short* __restrict__ alat) {
  const int t = blockIdx.y;
  const int tn = blockIdx.x * 128;  // c-dim tile
  __shared__ __align__(16) unsigned short As[128 * 32];
  __shared__ __align__(16) unsigned short St[32 * 128];
  __shared__ __align__(16) unsigned short Bs[128 * BSTRIDE];
  const int tid = threadIdx.x;
  const int lane = tid & 63, wave = tid >> 6;
  const int wm = (wave & 1) * 64, wn = (wave >> 1) * 64;
  const int l15 = lane & 15, quad = lane >> 4;
  const int r0 = tid >> 2, cg = tid & 3;
  const unsigned short* a0 = P + ((size_t)t * 128 + r0) * 512 + cg * 8;
  const unsigned short* a1 = a0 + (size_t)64 * 512;
  const int key0 = tid >> 4;  // 0..15 (and +16)
  const int cs = tid & 15;    // uint4 slot in the 128-c row
  const int* tkrow = topk + t * 512;
  floatx4 acc[4][4] = {};
  for (int ks = 0; ks < 16; ++ks) {  // contraction 512 keys = 16*32
    // A staging (vector, conflict-free)
    stage8_bf(a0 + ks * 32, &As[r0 * 32 + cg * 8]);
    stage8_bf(a1 + ks * 32, &As[(r0 + 64) * 32 + cg * 8]);
    // B gather into St (coalesced 16B per lane; 16 lanes cover one key row)
    {
      const int i0 = tkrow[ks * 32 + key0];
      const int i1 = tkrow[ks * 32 + key0 + 16];
      *reinterpret_cast<uint4*>(&St[key0 * 128 + cs * 8]) =
          *reinterpret_cast<const uint4*>(kvb + (size_t)i0 * 576 + tn + cs * 8);
      *reinterpret_cast<uint4*>(&St[(key0 + 16) * 128 + cs * 8]) =
          *reinterpret_cast<const uint4*>(kvb + (size_t)i1 * 576 + tn + cs * 8);
    }
    __syncthreads();
    // transpose St -> Bs: task p: c = p&127, kg = p>>7 (8 keys each)
#pragma unroll
    for (int it = 0; it < 2; ++it) {
      const int p = it * 256 + tid;
      const int c = p & 127;
      const int kg = p >> 7;  // 0..3
      unsigned short tmp[8];
#pragma unroll
      for (int i = 0; i < 8; ++i) tmp[i] = St[(kg * 8 + i) * 128 + c];
      *reinterpret_cast<uint4*>(&Bs[c * BSTRIDE + kg * 8]) =
          *reinterpret_cast<const uint4*>(tmp);
    }
    __syncthreads();
    mfma_4x4_s(As, Bs, wm, wn, l15, quad, BSTRIDE, acc);
    __syncthreads();
  }
  // write attn_lat in (H, T, 512) layout for K5's contiguous A reads
#pragma unroll
  for (int i = 0; i < 4; ++i) {
    const int row = wm + i * 16 + quad * 4;  // head
#pragma unroll
    for (int j = 0; j < 4; ++j) {
      const int col = tn + wn + j * 16 + l15;  // c
#pragma unroll
      for (int r = 0; r < 4; ++r)
        alat[((size_t)(row + r) * 512 + t) * 512 + col] = f2bf(acc[i][j][r]);
    }
  }
}

// ---------------- K5: out (128t x 128v tile) = attn_lat[h] @ v_b[h]^T ----------------
__global__ __launch_bounds__(256) void out_gemm(const unsigned short* __restrict__ alat,
                                                const float* __restrict__ vb,
                                                float* __restrict__ out) {
  const int h = blockIdx.y;
  const int tm = blockIdx.x * 128;  // token tile
  __shared__ __align__(16) unsigned short As[128 * 32];
  __shared__ __align__(16) unsigned short Bs[128 * 32];
  const int tid = threadIdx.x;
  const int lane = tid & 63, wave = tid >> 6;
  const int wm = (wave & 1) * 64, wn = (wave >> 1) * 64;
  const int l15 = lane & 15, quad = lane >> 4;
  const int r0 = tid >> 2, cg = tid & 3;
  const unsigned short* a0 = alat + ((size_t)h * 512 + tm + r0) * 512 + cg * 8;
  const unsigned short* a1 = a0 + (size_t)64 * 512;
  const float* b0 = vb + ((size_t)h * 128 + r0) * 512 + cg * 8;
  const float* b1 = b0 + (size_t)64 * 512;
  floatx4 acc[4][4] = {};
  for (int ks = 0; ks < 16; ++ks) {  // contraction 512 = 16*32
    stage8_bf(a0 + ks * 32, &As[r0 * 32 + cg * 8]);
    stage8_bf(a1 + ks * 32, &As[(r0 + 64) * 32 + cg * 8]);
    stage8_f32(b0 + ks * 32, &Bs[r0 * 32 + cg * 8]);
    stage8_f32(b1 + ks * 32, &Bs[(r0 + 64) * 32 + cg * 8]);
    __syncthreads();
    mfma_4x4(As, Bs, wm, wn, l15, quad, acc);
    __syncthreads();
  }
#pragma unroll
  for (int i = 0; i < 4; ++i) {
    const int row = wm + i * 16 + quad * 4;  // token-local
#pragma unroll
    for (int j = 0; j < 4; ++j) {
      const int col = wn + j * 16 + l15;  // v
#pragma unroll
      for (int r = 0; r < 4; ++r) {
        const int t = tm + row + r;
        out[((size_t)t * 128 + h) * 128 + col] = acc[i][j][r];
      }
    }
  }
}

extern "C" void kernel_launch(void* const* d_in, const int* in_sizes, int n_in,
                              void* d_out, int out_size, void* d_ws, size_t ws_size,
                              hipStream_t stream) {
  const float* q = (const float*)d_in[0];         // (512,128,192)
  const float* kv = (const float*)d_in[1];        // (8192,576)
  const int* topk = (const int*)d_in[2];          // (512,512)
  const float* kb = (const float*)d_in[3];        // (128,512,128)
  const float* vb = (const float*)d_in[4];        // (128,128,512)
  float* out = (float*)d_out;                     // (512,128,128)

  char* ws = (char*)d_ws;
  unsigned short* kvb = (unsigned short*)ws;                              // 9,437,184 B
  unsigned short* qc = (unsigned short*)(ws + 9437184);                   // 75,497,472 B
  unsigned short* alat = qc;                                              // reuse (67,108,864 B)
  unsigned short* P = (unsigned short*)(ws + 9437184 + 75497472);         // 67,108,864 B
  // total ws need: 152,043,520 B

  kv_convert<<<dim3(4608), dim3(256), 0, stream>>>(kv, kvb);
  rope_copy<<<dim3(16384), dim3(256), 0, stream>>>(q, qc);
  qlat_gemm<<<dim3(16, 128), dim3(256), 0, stream>>>(q, kb, qc);
  scores_gemm<<<dim3(4, 512), dim3(256), 0, stream>>>(qc, kvb, topk, P);
  softmax_rows<<<dim3(16384), dim3(256), 0, stream>>>(P);
  attn_gemm<<<dim3(4, 512), dim3(256), 0, stream>>>(P, kvb, topk, alat);
  out_gemm<<<dim3(4, 128), dim3(256), 0, stream>>>(alat, vb, out);
}

// Round 3
// 399.965 us; speedup vs baseline: 1.1869x; 1.0070x over previous
//
#include <hip/hip_runtime.h>
#include <stdint.h>

// DSA sparse attention, MI355X. T=512 tok, H=128 heads, K=512 selected keys,
// C=576 (512 lora + 64 rope), S=8192 cache rows.
// Pipeline: kv->bf16, rope copy (SCALE folded), q_lat GEMM, scores GEMM,
// row softmax, attn GEMM, out GEMM. All GEMMs: 128x128 tile, BK=32,
// 4 waves x (4x4 of 16x16x32 bf16 MFMA), verified m90/m92 layout:
// A[m=lane&15][k=quad*8+j], B[n=lane&15][k=quad*8+j], D col=lane&15 row=quad*4+reg.
//
// R1->R2: attn_gemm 32-way LDS write conflicts fixed (stage+padded transpose).
// R2->R3: (a) XCD swizzle: blocks sharing an A-tile get the same linear-id mod 8
//         (grid x = t or h) so the shared tile is fetched into ONE XCD L2, not 4
//         (scores FETCH was 246MB vs 85MB unique).
//         (b) global_load_lds width=16 staging (m93->m97 lever) for scores A/B,
//         attn A/St-gather, out A. LDS dest = wave-uniform base + lane*16:
//         all staging layouts are As[tid*8] shorts = tid*16 bytes, contiguous.

#define SCALE 0.041666666666666664f  // (512+64)^-0.5

typedef __bf16 bf16x8 __attribute__((ext_vector_type(8)));
typedef float floatx4 __attribute__((ext_vector_type(4)));

static __device__ __forceinline__ unsigned short f2bf(float f) {
  unsigned int u = __builtin_bit_cast(unsigned int, f);
  u += 0x7FFF + ((u >> 16) & 1);  // RNE
  return (unsigned short)(u >> 16);
}
static __device__ __forceinline__ float bf2f(unsigned short h) {
  unsigned int u = ((unsigned int)h) << 16;
  return __builtin_bit_cast(float, u);
}
static __device__ __forceinline__ unsigned int pack2(float lo, float hi) {
  return (unsigned int)f2bf(lo) | ((unsigned int)f2bf(hi) << 16);
}
// async global->LDS, 16B per lane; LDS dest = wave base + lane*16 (m97 pattern)
static __device__ __forceinline__ void ldsdma16(const void* g, void* l) {
  __builtin_amdgcn_global_load_lds(
      (const __attribute__((address_space(1))) void*)g,
      (__attribute__((address_space(3))) void*)l, 16, 0, 0);
}
// stage 8 fp32 -> 8 bf16 into LDS (16B aligned)
static __device__ __forceinline__ void stage8_f32(const float* __restrict__ src,
                                                  unsigned short* dst) {
  const float4* s4 = reinterpret_cast<const float4*>(src);
  float4 v0 = s4[0], v1 = s4[1];
  uint4 o;
  o.x = pack2(v0.x, v0.y); o.y = pack2(v0.z, v0.w);
  o.z = pack2(v1.x, v1.y); o.w = pack2(v1.z, v1.w);
  *reinterpret_cast<uint4*>(dst) = o;
}
// stage 8 bf16 -> LDS (plain 16B copy)
static __device__ __forceinline__ void stage8_bf(const unsigned short* __restrict__ src,
                                                 unsigned short* dst) {
  *reinterpret_cast<uint4*>(dst) = *reinterpret_cast<const uint4*>(src);
}

static __device__ __forceinline__ void mfma_4x4_s(const unsigned short* As,
                                                  const unsigned short* Bs,
                                                  int wm, int wn, int l15, int quad,
                                                  int bstride, floatx4 acc[4][4]) {
  bf16x8 af[4], bfr[4];
#pragma unroll
  for (int i = 0; i < 4; ++i)
    af[i] = *reinterpret_cast<const bf16x8*>(&As[(wm + i * 16 + l15) * 32 + quad * 8]);
#pragma unroll
  for (int j = 0; j < 4; ++j)
    bfr[j] = *reinterpret_cast<const bf16x8*>(&Bs[(wn + j * 16 + l15) * bstride + quad * 8]);
#pragma unroll
  for (int i = 0; i < 4; ++i)
#pragma unroll
    for (int j = 0; j < 4; ++j)
      acc[i][j] = __builtin_amdgcn_mfma_f32_16x16x32_bf16(af[i], bfr[j], acc[i][j], 0, 0, 0);
}
static __device__ __forceinline__ void mfma_4x4(const unsigned short* As,
                                                const unsigned short* Bs,
                                                int wm, int wn, int l15, int quad,
                                                floatx4 acc[4][4]) {
  mfma_4x4_s(As, Bs, wm, wn, l15, quad, 32, acc);
}

// ---------------- K0a: kv_cache fp32 -> bf16 ----------------
__global__ void kv_convert(const float* __restrict__ kv, unsigned short* __restrict__ kvb) {
  int i = blockIdx.x * 256 + threadIdx.x;  // per 4 elems, grid sized exactly
  float4 v = reinterpret_cast<const float4*>(kv)[i];
  ushort4 o;
  o.x = f2bf(v.x); o.y = f2bf(v.y); o.z = f2bf(v.z); o.w = f2bf(v.w);
  reinterpret_cast<ushort4*>(kvb)[i] = o;
}

// ---------------- K0b: q_rope * SCALE -> q_concat[..., 512:576] ----------------
__global__ void rope_copy(const float* __restrict__ q, unsigned short* __restrict__ qc) {
  int i = blockIdx.x * 256 + threadIdx.x;  // 512*128*64 total
  int r = i & 63;
  int th = i >> 6;  // t*128 + h
  qc[(size_t)th * 576 + 512 + r] = f2bf(q[(size_t)th * 192 + 128 + r] * SCALE);
}

// ---------------- K1: q_lat = per-head (T x 128) @ (512 x 128)^T, * SCALE ----------------
// grid (128, 16): x = h so all 16 tile-blocks of one head share an XCD L2.
__global__ __launch_bounds__(256) void qlat_gemm(const float* __restrict__ q,
                                                 const float* __restrict__ kb,
                                                 unsigned short* __restrict__ qc) {
  const int h = blockIdx.x;
  const int tm = (blockIdx.y & 3) * 128;   // token tile
  const int tn = (blockIdx.y >> 2) * 128;  // lora-dim tile
  __shared__ __align__(16) unsigned short As[128 * 32];
  __shared__ __align__(16) unsigned short Bs[128 * 32];
  const int tid = threadIdx.x;
  const int lane = tid & 63, wave = tid >> 6;
  const int wm = (wave & 1) * 64, wn = (wave >> 1) * 64;
  const int l15 = lane & 15, quad = lane >> 4;
  const int r0 = tid >> 2, cg = tid & 3;  // chunk row, col-group(8); +256 chunk = row+64
  const float* a0 = q + ((size_t)(tm + r0) * 128 + h) * 192 + cg * 8;
  const float* a1 = q + ((size_t)(tm + r0 + 64) * 128 + h) * 192 + cg * 8;
  const float* b0 = kb + ((size_t)h * 512 + tn + r0) * 128 + cg * 8;
  const float* b1 = b0 + (size_t)64 * 128;
  floatx4 acc[4][4] = {};
  for (int ks = 0; ks < 4; ++ks) {  // contraction 128 = 4*32
    stage8_f32(a0 + ks * 32, &As[tid * 8]);
    stage8_f32(a1 + ks * 32, &As[2048 + tid * 8]);
    stage8_f32(b0 + ks * 32, &Bs[tid * 8]);
    stage8_f32(b1 + ks * 32, &Bs[2048 + tid * 8]);
    __syncthreads();
    mfma_4x4(As, Bs, wm, wn, l15, quad, acc);
    __syncthreads();
  }
#pragma unroll
  for (int i = 0; i < 4; ++i) {
    const int row = wm + i * 16 + quad * 4;  // token-local
#pragma unroll
    for (int j = 0; j < 4; ++j) {
      const int col = wn + j * 16 + l15;  // lora-dim-local
#pragma unroll
      for (int r = 0; r < 4; ++r) {
        const int t = tm + row + r;
        qc[((size_t)t * 128 + h) * 576 + tn + col] = f2bf(acc[i][j][r] * SCALE);
      }
    }
  }
}

// ---------------- K2: scores (128h x 128key tile) = Qc @ KVsel^T ----------------
// grid (512, 4): x = t so the 4 key-tile blocks sharing A[t] share an XCD L2.
__global__ __launch_bounds__(256) void scores_gemm(const unsigned short* __restrict__ qc,
                                                   const unsigned short* __restrict__ kvb,
                                                   const int* __restrict__ topk,
                                                   unsigned short* __restrict__ P) {
  const int t = blockIdx.x;
  const int tn = blockIdx.y * 128;  // key tile
  __shared__ __align__(16) unsigned short As[128 * 32];
  __shared__ __align__(16) unsigned short Bs[128 * 32];
  const int tid = threadIdx.x;
  const int lane = tid & 63, wave = tid >> 6;
  const int wm = (wave & 1) * 64, wn = (wave >> 1) * 64;
  const int l15 = lane & 15, quad = lane >> 4;
  const int r0 = tid >> 2, cg = tid & 3;
  const unsigned short* a0 = qc + ((size_t)t * 128 + r0) * 576 + cg * 8;
  const unsigned short* a1 = a0 + (size_t)64 * 576;
  const int idx0 = topk[t * 512 + tn + r0];
  const int idx1 = topk[t * 512 + tn + r0 + 64];
  const unsigned short* b0 = kvb + (size_t)idx0 * 576 + cg * 8;
  const unsigned short* b1 = kvb + (size_t)idx1 * 576 + cg * 8;
  floatx4 acc[4][4] = {};
  for (int ks = 0; ks < 18; ++ks) {  // contraction 576 = 18*32
    ldsdma16(a0 + ks * 32, &As[tid * 8]);
    ldsdma16(a1 + ks * 32, &As[2048 + tid * 8]);
    ldsdma16(b0 + ks * 32, &Bs[tid * 8]);
    ldsdma16(b1 + ks * 32, &Bs[2048 + tid * 8]);
    __syncthreads();
    mfma_4x4(As, Bs, wm, wn, l15, quad, acc);
    __syncthreads();
  }
#pragma unroll
  for (int i = 0; i < 4; ++i) {
    const int row = wm + i * 16 + quad * 4;  // head
#pragma unroll
    for (int j = 0; j < 4; ++j) {
      const int col = tn + wn + j * 16 + l15;  // key
#pragma unroll
      for (int r = 0; r < 4; ++r)
        P[((size_t)t * 128 + row + r) * 512 + col] = f2bf(acc[i][j][r]);
    }
  }
}

// ---------------- K3: in-place softmax over rows of 512 (one wave per row) ----------------
__global__ __launch_bounds__(256) void softmax_rows(unsigned short* __restrict__ P) {
  const int row = blockIdx.x * 4 + (threadIdx.x >> 6);
  const int lane = threadIdx.x & 63;
  unsigned short* rp = P + (size_t)row * 512 + lane * 8;
  uint4 raw = *reinterpret_cast<const uint4*>(rp);
  unsigned int w[4] = {raw.x, raw.y, raw.z, raw.w};
  float f[8];
  float mx = -1e30f;
#pragma unroll
  for (int i = 0; i < 8; ++i) {
    f[i] = bf2f((unsigned short)((w[i >> 1] >> ((i & 1) * 16)) & 0xFFFF));
    mx = fmaxf(mx, f[i]);
  }
#pragma unroll
  for (int off = 32; off; off >>= 1) mx = fmaxf(mx, __shfl_xor(mx, off, 64));
  float s = 0.f;
#pragma unroll
  for (int i = 0; i < 8; ++i) { f[i] = __expf(f[i] - mx); s += f[i]; }
#pragma unroll
  for (int off = 32; off; off >>= 1) s += __shfl_xor(s, off, 64);
  const float inv = 1.0f / s;
  uint4 o;
  o.x = pack2(f[0] * inv, f[1] * inv);
  o.y = pack2(f[2] * inv, f[3] * inv);
  o.z = pack2(f[4] * inv, f[5] * inv);
  o.w = pack2(f[6] * inv, f[7] * inv);
  *reinterpret_cast<uint4*>(rp) = o;
}

// ---------------- K4: attn_lat (128h x 128c tile) = P @ KVsel[:, :512] ----------------
// grid (512, 4): x = t (shared A[t] per XCD). Conflict-free transpose:
//   St[32 key][128 c]  <- global_load_lds gather from kvb (16B/lane)
//   Bs[128 c][32 key]  <- transpose, row stride 40 shorts (80B): both writes
//                         and fragment reads spread over all 32 banks.
#define BSTRIDE 40
__global__ __launch_bounds__(256) void attn_gemm(const unsigned short* __restrict__ P,
                                                 const unsigned short* __restrict__ kvb,
                                                 const int* __restrict__ topk,
                                                 unsigned short* __restrict__ alat) {
  const int t = blockIdx.x;
  const int tn = blockIdx.y * 128;  // c-dim tile
  __shared__ __align__(16) unsigned short As[128 * 32];
  __shared__ __align__(16) unsigned short St[32 * 128];
  __shared__ __align__(16) unsigned short Bs[128 * BSTRIDE];
  const int tid = threadIdx.x;
  const int lane = tid & 63, wave = tid >> 6;
  const int wm = (wave & 1) * 64, wn = (wave >> 1) * 64;
  const int l15 = lane & 15, quad = lane >> 4;
  const unsigned short* a0 = P + ((size_t)t * 128 + (tid >> 2)) * 512 + (tid & 3) * 8;
  const unsigned short* a1 = a0 + (size_t)64 * 512;
  const int key0 = tid >> 4;  // 0..15 (and +16)
  const int cs = tid & 15;    // uint4 slot in the 128-c row
  const int* tkrow = topk + t * 512;
  floatx4 acc[4][4] = {};
  for (int ks = 0; ks < 16; ++ks) {  // contraction 512 keys = 16*32
    // A staging + B gather, all direct-to-LDS (dest = tid*16 bytes, contiguous)
    ldsdma16(a0 + ks * 32, &As[tid * 8]);
    ldsdma16(a1 + ks * 32, &As[2048 + tid * 8]);
    const int i0 = tkrow[ks * 32 + key0];
    const int i1 = tkrow[ks * 32 + key0 + 16];
    ldsdma16(kvb + (size_t)i0 * 576 + tn + cs * 8, &St[tid * 8]);
    ldsdma16(kvb + (size_t)i1 * 576 + tn + cs * 8, &St[2048 + tid * 8]);
    __syncthreads();
    // transpose St -> Bs: task p: c = p&127, kg = p>>7 (8 keys each)
#pragma unroll
    for (int it = 0; it < 2; ++it) {
      const int p = it * 256 + tid;
      const int c = p & 127;
      const int kg = p >> 7;  // 0..3
      unsigned short tmp[8];
#pragma unroll
      for (int i = 0; i < 8; ++i) tmp[i] = St[(kg * 8 + i) * 128 + c];
      *reinterpret_cast<uint4*>(&Bs[c * BSTRIDE + kg * 8]) =
          *reinterpret_cast<const uint4*>(tmp);
    }
    __syncthreads();
    mfma_4x4_s(As, Bs, wm, wn, l15, quad, BSTRIDE, acc);
    __syncthreads();
  }
  // write attn_lat in (H, T, 512) layout for K5's contiguous A reads
#pragma unroll
  for (int i = 0; i < 4; ++i) {
    const int row = wm + i * 16 + quad * 4;  // head
#pragma unroll
    for (int j = 0; j < 4; ++j) {
      const int col = tn + wn + j * 16 + l15;  // c
#pragma unroll
      for (int r = 0; r < 4; ++r)
        alat[((size_t)(row + r) * 512 + t) * 512 + col] = f2bf(acc[i][j][r]);
    }
  }
}

// ---------------- K5: out (128t x 128v tile) = attn_lat[h] @ v_b[h]^T ----------------
// grid (128, 4): x = h so the 4 token-tile blocks sharing B[h] share an XCD L2.
__global__ __launch_bounds__(256) void out_gemm(const unsigned short* __restrict__ alat,
                                                const float* __restrict__ vb,
                                                float* __restrict__ out) {
  const int h = blockIdx.x;
  const int tm = blockIdx.y * 128;  // token tile
  __shared__ __align__(16) unsigned short As[128 * 32];
  __shared__ __align__(16) unsigned short Bs[128 * 32];
  const int tid = threadIdx.x;
  const int lane = tid & 63, wave = tid >> 6;
  const int wm = (wave & 1) * 64, wn = (wave >> 1) * 64;
  const int l15 = lane & 15, quad = lane >> 4;
  const int r0 = tid >> 2, cg = tid & 3;
  const unsigned short* a0 = alat + ((size_t)h * 512 + tm + r0) * 512 + cg * 8;
  const unsigned short* a1 = a0 + (size_t)64 * 512;
  const float* b0 = vb + ((size_t)h * 128 + r0) * 512 + cg * 8;
  const float* b1 = b0 + (size_t)64 * 512;
  floatx4 acc[4][4] = {};
  for (int ks = 0; ks < 16; ++ks) {  // contraction 512 = 16*32
    ldsdma16(a0 + ks * 32, &As[tid * 8]);
    ldsdma16(a1 + ks * 32, &As[2048 + tid * 8]);
    stage8_f32(b0 + ks * 32, &Bs[tid * 8]);
    stage8_f32(b1 + ks * 32, &Bs[2048 + tid * 8]);
    __syncthreads();
    mfma_4x4(As, Bs, wm, wn, l15, quad, acc);
    __syncthreads();
  }
#pragma unroll
  for (int i = 0; i < 4; ++i) {
    const int row = wm + i * 16 + quad * 4;  // token-local
#pragma unroll
    for (int j = 0; j < 4; ++j) {
      const int col = wn + j * 16 + l15;  // v
#pragma unroll
      for (int r = 0; r < 4; ++r) {
        const int t = tm + row + r;
        out[((size_t)t * 128 + h) * 128 + col] = acc[i][j][r];
      }
    }
  }
}

extern "C" void kernel_launch(void* const* d_in, const int* in_sizes, int n_in,
                              void* d_out, int out_size, void* d_ws, size_t ws_size,
                              hipStream_t stream) {
  const float* q = (const float*)d_in[0];         // (512,128,192)
  const float* kv = (const float*)d_in[1];        // (8192,576)
  const int* topk = (const int*)d_in[2];          // (512,512)
  const float* kb = (const float*)d_in[3];        // (128,512,128)
  const float* vb = (const float*)d_in[4];        // (128,128,512)
  float* out = (float*)d_out;                     // (512,128,128)

  char* ws = (char*)d_ws;
  unsigned short* kvb = (unsigned short*)ws;                              // 9,437,184 B
  unsigned short* qc = (unsigned short*)(ws + 9437184);                   // 75,497,472 B
  unsigned short* alat = qc;                                              // reuse (67,108,864 B)
  unsigned short* P = (unsigned short*)(ws + 9437184 + 75497472);         // 67,108,864 B
  // total ws need: 152,043,520 B

  kv_convert<<<dim3(4608), dim3(256), 0, stream>>>(kv, kvb);
  rope_copy<<<dim3(16384), dim3(256), 0, stream>>>(q, qc);
  qlat_gemm<<<dim3(128, 16), dim3(256), 0, stream>>>(q, kb, qc);
  scores_gemm<<<dim3(512, 4), dim3(256), 0, stream>>>(qc, kvb, topk, P);
  softmax_rows<<<dim3(16384), dim3(256), 0, stream>>>(P);
  attn_gemm<<<dim3(512, 4), dim3(256), 0, stream>>>(P, kvb, topk, alat);
  out_gemm<<<dim3(128, 4), dim3(256), 0, stream>>>(alat, vb, out);
}

// Round 4
// 397.470 us; speedup vs baseline: 1.1943x; 1.0063x over previous
//
#include <hip/hip_runtime.h>
#include <stdint.h>

// DSA sparse attention, MI355X. T=512 tok, H=128 heads, K=512 selected keys,
// C=576 (512 lora + 64 rope), S=8192 cache rows.
// Pipeline: kv->bf16, rope copy (SCALE folded), q_lat GEMM, scores GEMM,
// row softmax, attn GEMM, out GEMM. All GEMMs: 128x128 tile, BK=32,
// 4 waves x (4x4 of 16x16x32 bf16 MFMA), verified m90/m92 layout:
// A[m=lane&15][k=quad*8+j], B[n=lane&15][k=quad*8+j], D col=lane&15 row=quad*4+reg.
//
// R1->R2: attn_gemm 32-way LDS write conflicts fixed (stage+padded transpose).
// R2->R3: XCD swizzle (grid x = shared-tile axis) + global_load_lds staging.
// R3->R4: attn_gemm transpose v3 (it was LDS-issue-bound: 16 u16 reads + 8-way
//         conflicted writes per thread per ks):
//         - c-pair b32 reads (8 instead of 16), St padded to stride 132 so
//           reads are <=2-way (free); St filled by vector loads (padded rows
//           are incompatible with the wave-uniform global_load_lds dest rule).
//         - transpose task (kg=tid&3, cpair=tid>>2): Bs b128 writes land
//           uniformly 8 words/bank (the floor) -> zero excess conflicts.

#define SCALE 0.041666666666666664f  // (512+64)^-0.5

typedef __bf16 bf16x8 __attribute__((ext_vector_type(8)));
typedef float floatx4 __attribute__((ext_vector_type(4)));

static __device__ __forceinline__ unsigned short f2bf(float f) {
  unsigned int u = __builtin_bit_cast(unsigned int, f);
  u += 0x7FFF + ((u >> 16) & 1);  // RNE
  return (unsigned short)(u >> 16);
}
static __device__ __forceinline__ float bf2f(unsigned short h) {
  unsigned int u = ((unsigned int)h) << 16;
  return __builtin_bit_cast(float, u);
}
static __device__ __forceinline__ unsigned int pack2(float lo, float hi) {
  return (unsigned int)f2bf(lo) | ((unsigned int)f2bf(hi) << 16);
}
// async global->LDS, 16B per lane; LDS dest = wave base + lane*16 (m97 pattern)
static __device__ __forceinline__ void ldsdma16(const void* g, void* l) {
  __builtin_amdgcn_global_load_lds(
      (const __attribute__((address_space(1))) void*)g,
      (__attribute__((address_space(3))) void*)l, 16, 0, 0);
}
// stage 8 fp32 -> 8 bf16 into LDS (16B aligned)
static __device__ __forceinline__ void stage8_f32(const float* __restrict__ src,
                                                  unsigned short* dst) {
  const float4* s4 = reinterpret_cast<const float4*>(src);
  float4 v0 = s4[0], v1 = s4[1];
  uint4 o;
  o.x = pack2(v0.x, v0.y); o.y = pack2(v0.z, v0.w);
  o.z = pack2(v1.x, v1.y); o.w = pack2(v1.z, v1.w);
  *reinterpret_cast<uint4*>(dst) = o;
}

static __device__ __forceinline__ void mfma_4x4_s(const unsigned short* As,
                                                  const unsigned short* Bs,
                                                  int wm, int wn, int l15, int quad,
                                                  int bstride, floatx4 acc[4][4]) {
  bf16x8 af[4], bfr[4];
#pragma unroll
  for (int i = 0; i < 4; ++i)
    af[i] = *reinterpret_cast<const bf16x8*>(&As[(wm + i * 16 + l15) * 32 + quad * 8]);
#pragma unroll
  for (int j = 0; j < 4; ++j)
    bfr[j] = *reinterpret_cast<const bf16x8*>(&Bs[(wn + j * 16 + l15) * bstride + quad * 8]);
#pragma unroll
  for (int i = 0; i < 4; ++i)
#pragma unroll
    for (int j = 0; j < 4; ++j)
      acc[i][j] = __builtin_amdgcn_mfma_f32_16x16x32_bf16(af[i], bfr[j], acc[i][j], 0, 0, 0);
}
static __device__ __forceinline__ void mfma_4x4(const unsigned short* As,
                                                const unsigned short* Bs,
                                                int wm, int wn, int l15, int quad,
                                                floatx4 acc[4][4]) {
  mfma_4x4_s(As, Bs, wm, wn, l15, quad, 32, acc);
}

// ---------------- K0a: kv_cache fp32 -> bf16 ----------------
__global__ void kv_convert(const float* __restrict__ kv, unsigned short* __restrict__ kvb) {
  int i = blockIdx.x * 256 + threadIdx.x;  // per 4 elems, grid sized exactly
  float4 v = reinterpret_cast<const float4*>(kv)[i];
  ushort4 o;
  o.x = f2bf(v.x); o.y = f2bf(v.y); o.z = f2bf(v.z); o.w = f2bf(v.w);
  reinterpret_cast<ushort4*>(kvb)[i] = o;
}

// ---------------- K0b: q_rope * SCALE -> q_concat[..., 512:576] ----------------
__global__ void rope_copy(const float* __restrict__ q, unsigned short* __restrict__ qc) {
  int i = blockIdx.x * 256 + threadIdx.x;  // 512*128*64 total
  int r = i & 63;
  int th = i >> 6;  // t*128 + h
  qc[(size_t)th * 576 + 512 + r] = f2bf(q[(size_t)th * 192 + 128 + r] * SCALE);
}

// ---------------- K1: q_lat = per-head (T x 128) @ (512 x 128)^T, * SCALE ----------------
// grid (128, 16): x = h so all 16 tile-blocks of one head share an XCD L2.
__global__ __launch_bounds__(256) void qlat_gemm(const float* __restrict__ q,
                                                 const float* __restrict__ kb,
                                                 unsigned short* __restrict__ qc) {
  const int h = blockIdx.x;
  const int tm = (blockIdx.y & 3) * 128;   // token tile
  const int tn = (blockIdx.y >> 2) * 128;  // lora-dim tile
  __shared__ __align__(16) unsigned short As[128 * 32];
  __shared__ __align__(16) unsigned short Bs[128 * 32];
  const int tid = threadIdx.x;
  const int lane = tid & 63, wave = tid >> 6;
  const int wm = (wave & 1) * 64, wn = (wave >> 1) * 64;
  const int l15 = lane & 15, quad = lane >> 4;
  const int r0 = tid >> 2, cg = tid & 3;  // chunk row, col-group(8); +256 chunk = row+64
  const float* a0 = q + ((size_t)(tm + r0) * 128 + h) * 192 + cg * 8;
  const float* a1 = q + ((size_t)(tm + r0 + 64) * 128 + h) * 192 + cg * 8;
  const float* b0 = kb + ((size_t)h * 512 + tn + r0) * 128 + cg * 8;
  const float* b1 = b0 + (size_t)64 * 128;
  floatx4 acc[4][4] = {};
  for (int ks = 0; ks < 4; ++ks) {  // contraction 128 = 4*32
    stage8_f32(a0 + ks * 32, &As[tid * 8]);
    stage8_f32(a1 + ks * 32, &As[2048 + tid * 8]);
    stage8_f32(b0 + ks * 32, &Bs[tid * 8]);
    stage8_f32(b1 + ks * 32, &Bs[2048 + tid * 8]);
    __syncthreads();
    mfma_4x4(As, Bs, wm, wn, l15, quad, acc);
    __syncthreads();
  }
#pragma unroll
  for (int i = 0; i < 4; ++i) {
    const int row = wm + i * 16 + quad * 4;  // token-local
#pragma unroll
    for (int j = 0; j < 4; ++j) {
      const int col = wn + j * 16 + l15;  // lora-dim-local
#pragma unroll
      for (int r = 0; r < 4; ++r) {
        const int t = tm + row + r;
        qc[((size_t)t * 128 + h) * 576 + tn + col] = f2bf(acc[i][j][r] * SCALE);
      }
    }
  }
}

// ---------------- K2: scores (128h x 128key tile) = Qc @ KVsel^T ----------------
// grid (512, 4): x = t so the 4 key-tile blocks sharing A[t] share an XCD L2.
__global__ __launch_bounds__(256) void scores_gemm(const unsigned short* __restrict__ qc,
                                                   const unsigned short* __restrict__ kvb,
                                                   const int* __restrict__ topk,
                                                   unsigned short* __restrict__ P) {
  const int t = blockIdx.x;
  const int tn = blockIdx.y * 128;  // key tile
  __shared__ __align__(16) unsigned short As[128 * 32];
  __shared__ __align__(16) unsigned short Bs[128 * 32];
  const int tid = threadIdx.x;
  const int lane = tid & 63, wave = tid >> 6;
  const int wm = (wave & 1) * 64, wn = (wave >> 1) * 64;
  const int l15 = lane & 15, quad = lane >> 4;
  const int r0 = tid >> 2, cg = tid & 3;
  const unsigned short* a0 = qc + ((size_t)t * 128 + r0) * 576 + cg * 8;
  const unsigned short* a1 = a0 + (size_t)64 * 576;
  const int idx0 = topk[t * 512 + tn + r0];
  const int idx1 = topk[t * 512 + tn + r0 + 64];
  const unsigned short* b0 = kvb + (size_t)idx0 * 576 + cg * 8;
  const unsigned short* b1 = kvb + (size_t)idx1 * 576 + cg * 8;
  floatx4 acc[4][4] = {};
  for (int ks = 0; ks < 18; ++ks) {  // contraction 576 = 18*32
    ldsdma16(a0 + ks * 32, &As[tid * 8]);
    ldsdma16(a1 + ks * 32, &As[2048 + tid * 8]);
    ldsdma16(b0 + ks * 32, &Bs[tid * 8]);
    ldsdma16(b1 + ks * 32, &Bs[2048 + tid * 8]);
    __syncthreads();
    mfma_4x4(As, Bs, wm, wn, l15, quad, acc);
    __syncthreads();
  }
#pragma unroll
  for (int i = 0; i < 4; ++i) {
    const int row = wm + i * 16 + quad * 4;  // head
#pragma unroll
    for (int j = 0; j < 4; ++j) {
      const int col = tn + wn + j * 16 + l15;  // key
#pragma unroll
      for (int r = 0; r < 4; ++r)
        P[((size_t)t * 128 + row + r) * 512 + col] = f2bf(acc[i][j][r]);
    }
  }
}

// ---------------- K3: in-place softmax over rows of 512 (one wave per row) ----------------
__global__ __launch_bounds__(256) void softmax_rows(unsigned short* __restrict__ P) {
  const int row = blockIdx.x * 4 + (threadIdx.x >> 6);
  const int lane = threadIdx.x & 63;
  unsigned short* rp = P + (size_t)row * 512 + lane * 8;
  uint4 raw = *reinterpret_cast<const uint4*>(rp);
  unsigned int w[4] = {raw.x, raw.y, raw.z, raw.w};
  float f[8];
  float mx = -1e30f;
#pragma unroll
  for (int i = 0; i < 8; ++i) {
    f[i] = bf2f((unsigned short)((w[i >> 1] >> ((i & 1) * 16)) & 0xFFFF));
    mx = fmaxf(mx, f[i]);
  }
#pragma unroll
  for (int off = 32; off; off >>= 1) mx = fmaxf(mx, __shfl_xor(mx, off, 64));
  float s = 0.f;
#pragma unroll
  for (int i = 0; i < 8; ++i) { f[i] = __expf(f[i] - mx); s += f[i]; }
#pragma unroll
  for (int off = 32; off; off >>= 1) s += __shfl_xor(s, off, 64);
  const float inv = 1.0f / s;
  uint4 o;
  o.x = pack2(f[0] * inv, f[1] * inv);
  o.y = pack2(f[2] * inv, f[3] * inv);
  o.z = pack2(f[4] * inv, f[5] * inv);
  o.w = pack2(f[6] * inv, f[7] * inv);
  *reinterpret_cast<uint4*>(rp) = o;
}

// ---------------- K4: attn_lat (128h x 128c tile) = P @ KVsel[:, :512] ----------------
// grid (512, 4): x = t (shared A[t] per XCD). Transpose v3 (see header).
//   St[32 key][128 c]  stride 132 shorts (padded): c-pair b32 reads <=2-way
//   Bs[128 c][32 key]  stride 40 shorts: b128 writes + fragment reads uniform
#define BSTRIDE 40
#define STSTRIDE 132
__global__ __launch_bounds__(256) void attn_gemm(const unsigned short* __restrict__ P,
                                                 const unsigned short* __restrict__ kvb,
                                                 const int* __restrict__ topk,
                                                 unsigned short* __restrict__ alat) {
  const int t = blockIdx.x;
  const int tn = blockIdx.y * 128;  // c-dim tile
  __shared__ __align__(16) unsigned short As[128 * 32];
  __shared__ __align__(16) unsigned short St[32 * STSTRIDE];
  __shared__ __align__(16) unsigned short Bs[128 * BSTRIDE];
  const int tid = threadIdx.x;
  const int lane = tid & 63, wave = tid >> 6;
  const int wm = (wave & 1) * 64, wn = (wave >> 1) * 64;
  const int l15 = lane & 15, quad = lane >> 4;
  const unsigned short* a0 = P + ((size_t)t * 128 + (tid >> 2)) * 512 + (tid & 3) * 8;
  const unsigned short* a1 = a0 + (size_t)64 * 512;
  const int key0 = tid >> 4;  // 0..15 (and +16)
  const int cs = tid & 15;    // uint4 slot in the 128-c row
  const int kgT = tid & 3;    // transpose: key-group 0..3 (8 keys)
  const int cp = tid >> 2;    // transpose: c-pair 0..63 (c = 2cp, 2cp+1)
  const int* tkrow = topk + t * 512;
  floatx4 acc[4][4] = {};
  for (int ks = 0; ks < 16; ++ks) {  // contraction 512 keys = 16*32
    // A staging direct-to-LDS (dest = tid*16 bytes, contiguous)
    ldsdma16(a0 + ks * 32, &As[tid * 8]);
    ldsdma16(a1 + ks * 32, &As[2048 + tid * 8]);
    // St fill via vector loads (padded rows incompatible with DMA dest rule)
    const int i0 = tkrow[ks * 32 + key0];
    const int i1 = tkrow[ks * 32 + key0 + 16];
    uint4 v0 = *reinterpret_cast<const uint4*>(kvb + (size_t)i0 * 576 + tn + cs * 8);
    uint4 v1 = *reinterpret_cast<const uint4*>(kvb + (size_t)i1 * 576 + tn + cs * 8);
    *reinterpret_cast<uint4*>(&St[key0 * STSTRIDE + cs * 8]) = v0;
    *reinterpret_cast<uint4*>(&St[(key0 + 16) * STSTRIDE + cs * 8]) = v1;
    __syncthreads();
    // transpose: thread (cp, kgT) reads 8 c-pair words, writes 2 b128 rows
    unsigned int w[8];
#pragma unroll
    for (int i = 0; i < 8; ++i)
      w[i] = *reinterpret_cast<const unsigned int*>(&St[(kgT * 8 + i) * STSTRIDE + cp * 2]);
    unsigned short r0[8], r1[8];
#pragma unroll
    for (int i = 0; i < 8; ++i) {
      r0[i] = (unsigned short)(w[i] & 0xFFFF);
      r1[i] = (unsigned short)(w[i] >> 16);
    }
    *reinterpret_cast<uint4*>(&Bs[(2 * cp) * BSTRIDE + kgT * 8]) =
        *reinterpret_cast<const uint4*>(r0);
    *reinterpret_cast<uint4*>(&Bs[(2 * cp + 1) * BSTRIDE + kgT * 8]) =
        *reinterpret_cast<const uint4*>(r1);
    __syncthreads();
    mfma_4x4_s(As, Bs, wm, wn, l15, quad, BSTRIDE, acc);
    __syncthreads();
  }
  // write attn_lat in (H, T, 512) layout for K5's contiguous A reads
#pragma unroll
  for (int i = 0; i < 4; ++i) {
    const int row = wm + i * 16 + quad * 4;  // head
#pragma unroll
    for (int j = 0; j < 4; ++j) {
      const int col = tn + wn + j * 16 + l15;  // c
#pragma unroll
      for (int r = 0; r < 4; ++r)
        alat[((size_t)(row + r) * 512 + t) * 512 + col] = f2bf(acc[i][j][r]);
    }
  }
}

// ---------------- K5: out (128t x 128v tile) = attn_lat[h] @ v_b[h]^T ----------------
// grid (128, 4): x = h so the 4 token-tile blocks sharing B[h] share an XCD L2.
__global__ __launch_bounds__(256) void out_gemm(const unsigned short* __restrict__ alat,
                                                const float* __restrict__ vb,
                                                float* __restrict__ out) {
  const int h = blockIdx.x;
  const int tm = blockIdx.y * 128;  // token tile
  __shared__ __align__(16) unsigned short As[128 * 32];
  __shared__ __align__(16) unsigned short Bs[128 * 32];
  const int tid = threadIdx.x;
  const int lane = tid & 63, wave = tid >> 6;
  const int wm = (wave & 1) * 64, wn = (wave >> 1) * 64;
  const int l15 = lane & 15, quad = lane >> 4;
  const int r0 = tid >> 2, cg = tid & 3;
  const unsigned short* a0 = alat + ((size_t)h * 512 + tm + r0) * 512 + cg * 8;
  const unsigned short* a1 = a0 + (size_t)64 * 512;
  const float* b0 = vb + ((size_t)h * 128 + r0) * 512 + cg * 8;
  const float* b1 = b0 + (size_t)64 * 512;
  floatx4 acc[4][4] = {};
  for (int ks = 0; ks < 16; ++ks) {  // contraction 512 = 16*32
    ldsdma16(a0 + ks * 32, &As[tid * 8]);
    ldsdma16(a1 + ks * 32, &As[2048 + tid * 8]);
    stage8_f32(b0 + ks * 32, &Bs[tid * 8]);
    stage8_f32(b1 + ks * 32, &Bs[2048 + tid * 8]);
    __syncthreads();
    mfma_4x4(As, Bs, wm, wn, l15, quad, acc);
    __syncthreads();
  }
#pragma unroll
  for (int i = 0; i < 4; ++i) {
    const int row = wm + i * 16 + quad * 4;  // token-local
#pragma unroll
    for (int j = 0; j < 4; ++j) {
      const int col = wn + j * 16 + l15;  // v
#pragma unroll
      for (int r = 0; r < 4; ++r) {
        const int t = tm + row + r;
        out[((size_t)t * 128 + h) * 128 + col] = acc[i][j][r];
      }
    }
  }
}

extern "C" void kernel_launch(void* const* d_in, const int* in_sizes, int n_in,
                              void* d_out, int out_size, void* d_ws, size_t ws_size,
                              hipStream_t stream) {
  const float* q = (const float*)d_in[0];         // (512,128,192)
  const float* kv = (const float*)d_in[1];        // (8192,576)
  const int* topk = (const int*)d_in[2];          // (512,512)
  const float* kb = (const float*)d_in[3];        // (128,512,128)
  const float* vb = (const float*)d_in[4];        // (128,128,512)
  float* out = (float*)d_out;                     // (512,128,128)

  char* ws = (char*)d_ws;
  unsigned short* kvb = (unsigned short*)ws;                              // 9,437,184 B
  unsigned short* qc = (unsigned short*)(ws + 9437184);                   // 75,497,472 B
  unsigned short* alat = qc;                                              // reuse (67,108,864 B)
  unsigned short* P = (unsigned short*)(ws + 9437184 + 75497472);         // 67,108,864 B
  // total ws need: 152,043,520 B

  kv_convert<<<dim3(4608), dim3(256), 0, stream>>>(kv, kvb);
  rope_copy<<<dim3(16384), dim3(256), 0, stream>>>(q, qc);
  qlat_gemm<<<dim3(128, 16), dim3(256), 0, stream>>>(q, kb, qc);
  scores_gemm<<<dim3(512, 4), dim3(256), 0, stream>>>(qc, kvb, topk, P);
  softmax_rows<<<dim3(16384), dim3(256), 0, stream>>>(P);
  attn_gemm<<<dim3(512, 4), dim3(256), 0, stream>>>(P, kvb, topk, alat);
  out_gemm<<<dim3(128, 4), dim3(256), 0, stream>>>(alat, vb, out);
}

// Round 5
// 393.107 us; speedup vs baseline: 1.2076x; 1.0111x over previous
//
#include <hip/hip_runtime.h>
#include <stdint.h>

// DSA sparse attention, MI355X. T=512 tok, H=128 heads, K=512 selected keys,
// C=576 (512 lora + 64 rope), S=8192 cache rows.
// Pipeline: kv->bf16, rope copy (SCALE folded), q_lat GEMM, scores GEMM,
// row softmax (writes A-fragment-swizzled P2), attn GEMM, out GEMM.
// GEMMs: 128x128 tile, BK=32, 4 waves x (4x4 of 16x16x32 bf16 MFMA), m90/m92:
// A[m=lane&15][k=quad*8+j], B[n=lane&15][k=quad*8+j], D col=lane&15 row=quad*4+reg.
//
// R1->R2: attn 32-way LDS write conflicts fixed (stage+padded transpose).
// R2->R3: XCD swizzle (grid x = shared-tile axis) + global_load_lds staging.
// R3->R4: transpose bank tuning - NEUTRAL: kernel is LDS-issue/critical-path
//         bound (~760 LDS cyc/CU/ks vs 80 MFMA cyc), not conflict-bound.
// R4->R5: attn v4 - remove A from LDS entirely: softmax writes P2 in MFMA
//         A-fragment order [t][ks][h][key&31], attn loads A-fragments straight
//         from global (1KB contiguous per wave per fragment) with register
//         prefetch; St double-buffered via DMA issued after the Bs barrier so
//         gather latency overlaps MFMA; 2 barriers/ks (was 3).
//         ws re-use: P2 -> dead qc region, alat -> dead P region (total 152MB).

#define SCALE 0.041666666666666664f  // (512+64)^-0.5

typedef __bf16 bf16x8 __attribute__((ext_vector_type(8)));
typedef float floatx4 __attribute__((ext_vector_type(4)));

static __device__ __forceinline__ unsigned short f2bf(float f) {
  unsigned int u = __builtin_bit_cast(unsigned int, f);
  u += 0x7FFF + ((u >> 16) & 1);  // RNE
  return (unsigned short)(u >> 16);
}
static __device__ __forceinline__ float bf2f(unsigned short h) {
  unsigned int u = ((unsigned int)h) << 16;
  return __builtin_bit_cast(float, u);
}
static __device__ __forceinline__ unsigned int pack2(float lo, float hi) {
  return (unsigned int)f2bf(lo) | ((unsigned int)f2bf(hi) << 16);
}
// async global->LDS, 16B per lane; LDS dest = wave base + lane*16 (m97 pattern)
static __device__ __forceinline__ void ldsdma16(const void* g, void* l) {
  __builtin_amdgcn_global_load_lds(
      (const __attribute__((address_space(1))) void*)g,
      (__attribute__((address_space(3))) void*)l, 16, 0, 0);
}
// stage 8 fp32 -> 8 bf16 into LDS (16B aligned)
static __device__ __forceinline__ void stage8_f32(const float* __restrict__ src,
                                                  unsigned short* dst) {
  const float4* s4 = reinterpret_cast<const float4*>(src);
  float4 v0 = s4[0], v1 = s4[1];
  uint4 o;
  o.x = pack2(v0.x, v0.y); o.y = pack2(v0.z, v0.w);
  o.z = pack2(v1.x, v1.y); o.w = pack2(v1.z, v1.w);
  *reinterpret_cast<uint4*>(dst) = o;
}

static __device__ __forceinline__ void mfma_4x4(const unsigned short* As,
                                                const unsigned short* Bs,
                                                int wm, int wn, int l15, int quad,
                                                floatx4 acc[4][4]) {
  bf16x8 af[4], bfr[4];
#pragma unroll
  for (int i = 0; i < 4; ++i)
    af[i] = *reinterpret_cast<const bf16x8*>(&As[(wm + i * 16 + l15) * 32 + quad * 8]);
#pragma unroll
  for (int j = 0; j < 4; ++j)
    bfr[j] = *reinterpret_cast<const bf16x8*>(&Bs[(wn + j * 16 + l15) * 32 + quad * 8]);
#pragma unroll
  for (int i = 0; i < 4; ++i)
#pragma unroll
    for (int j = 0; j < 4; ++j)
      acc[i][j] = __builtin_amdgcn_mfma_f32_16x16x32_bf16(af[i], bfr[j], acc[i][j], 0, 0, 0);
}

// ---------------- K0a: kv_cache fp32 -> bf16 ----------------
__global__ void kv_convert(const float* __restrict__ kv, unsigned short* __restrict__ kvb) {
  int i = blockIdx.x * 256 + threadIdx.x;  // per 4 elems, grid sized exactly
  float4 v = reinterpret_cast<const float4*>(kv)[i];
  ushort4 o;
  o.x = f2bf(v.x); o.y = f2bf(v.y); o.z = f2bf(v.z); o.w = f2bf(v.w);
  reinterpret_cast<ushort4*>(kvb)[i] = o;
}

// ---------------- K0b: q_rope * SCALE -> q_concat[..., 512:576] ----------------
__global__ void rope_copy(const float* __restrict__ q, unsigned short* __restrict__ qc) {
  int i = blockIdx.x * 256 + threadIdx.x;  // 512*128*64 total
  int r = i & 63;
  int th = i >> 6;  // t*128 + h
  qc[(size_t)th * 576 + 512 + r] = f2bf(q[(size_t)th * 192 + 128 + r] * SCALE);
}

// ---------------- K1: q_lat = per-head (T x 128) @ (512 x 128)^T, * SCALE ----------------
// grid (128, 16): x = h so all 16 tile-blocks of one head share an XCD L2.
__global__ __launch_bounds__(256) void qlat_gemm(const float* __restrict__ q,
                                                 const float* __restrict__ kb,
                                                 unsigned short* __restrict__ qc) {
  const int h = blockIdx.x;
  const int tm = (blockIdx.y & 3) * 128;   // token tile
  const int tn = (blockIdx.y >> 2) * 128;  // lora-dim tile
  __shared__ __align__(16) unsigned short As[128 * 32];
  __shared__ __align__(16) unsigned short Bs[128 * 32];
  const int tid = threadIdx.x;
  const int lane = tid & 63, wave = tid >> 6;
  const int wm = (wave & 1) * 64, wn = (wave >> 1) * 64;
  const int l15 = lane & 15, quad = lane >> 4;
  const int r0 = tid >> 2, cg = tid & 3;  // chunk row, col-group(8)
  const float* a0 = q + ((size_t)(tm + r0) * 128 + h) * 192 + cg * 8;
  const float* a1 = q + ((size_t)(tm + r0 + 64) * 128 + h) * 192 + cg * 8;
  const float* b0 = kb + ((size_t)h * 512 + tn + r0) * 128 + cg * 8;
  const float* b1 = b0 + (size_t)64 * 128;
  floatx4 acc[4][4] = {};
  for (int ks = 0; ks < 4; ++ks) {  // contraction 128 = 4*32
    stage8_f32(a0 + ks * 32, &As[tid * 8]);
    stage8_f32(a1 + ks * 32, &As[2048 + tid * 8]);
    stage8_f32(b0 + ks * 32, &Bs[tid * 8]);
    stage8_f32(b1 + ks * 32, &Bs[2048 + tid * 8]);
    __syncthreads();
    mfma_4x4(As, Bs, wm, wn, l15, quad, acc);
    __syncthreads();
  }
#pragma unroll
  for (int i = 0; i < 4; ++i) {
    const int row = wm + i * 16 + quad * 4;  // token-local
#pragma unroll
    for (int j = 0; j < 4; ++j) {
      const int col = wn + j * 16 + l15;  // lora-dim-local
#pragma unroll
      for (int r = 0; r < 4; ++r) {
        const int t = tm + row + r;
        qc[((size_t)t * 128 + h) * 576 + tn + col] = f2bf(acc[i][j][r] * SCALE);
      }
    }
  }
}

// ---------------- K2: scores (128h x 128key tile) = Qc @ KVsel^T ----------------
// grid (512, 4): x = t so the 4 key-tile blocks sharing A[t] share an XCD L2.
__global__ __launch_bounds__(256) void scores_gemm(const unsigned short* __restrict__ qc,
                                                   const unsigned short* __restrict__ kvb,
                                                   const int* __restrict__ topk,
                                                   unsigned short* __restrict__ P) {
  const int t = blockIdx.x;
  const int tn = blockIdx.y * 128;  // key tile
  __shared__ __align__(16) unsigned short As[128 * 32];
  __shared__ __align__(16) unsigned short Bs[128 * 32];
  const int tid = threadIdx.x;
  const int lane = tid & 63, wave = tid >> 6;
  const int wm = (wave & 1) * 64, wn = (wave >> 1) * 64;
  const int l15 = lane & 15, quad = lane >> 4;
  const int r0 = tid >> 2, cg = tid & 3;
  const unsigned short* a0 = qc + ((size_t)t * 128 + r0) * 576 + cg * 8;
  const unsigned short* a1 = a0 + (size_t)64 * 576;
  const int idx0 = topk[t * 512 + tn + r0];
  const int idx1 = topk[t * 512 + tn + r0 + 64];
  const unsigned short* b0 = kvb + (size_t)idx0 * 576 + cg * 8;
  const unsigned short* b1 = kvb + (size_t)idx1 * 576 + cg * 8;
  floatx4 acc[4][4] = {};
  for (int ks = 0; ks < 18; ++ks) {  // contraction 576 = 18*32
    ldsdma16(a0 + ks * 32, &As[tid * 8]);
    ldsdma16(a1 + ks * 32, &As[2048 + tid * 8]);
    ldsdma16(b0 + ks * 32, &Bs[tid * 8]);
    ldsdma16(b1 + ks * 32, &Bs[2048 + tid * 8]);
    __syncthreads();
    mfma_4x4(As, Bs, wm, wn, l15, quad, acc);
    __syncthreads();
  }
#pragma unroll
  for (int i = 0; i < 4; ++i) {
    const int row = wm + i * 16 + quad * 4;  // head
#pragma unroll
    for (int j = 0; j < 4; ++j) {
      const int col = tn + wn + j * 16 + l15;  // key
#pragma unroll
      for (int r = 0; r < 4; ++r)
        P[((size_t)t * 128 + row + r) * 512 + col] = f2bf(acc[i][j][r]);
    }
  }
}

// ---------------- K3: softmax rows of 512; writes P2 in A-fragment order ----------------
// P2 layout: [t][ks=key>>5][h][key&31]; lane l holds keys 8l..8l+7 so the
// write is one uint4 at ((t*16 + (l>>2))*128 + h)*32 + (l&3)*8.
__global__ __launch_bounds__(256) void softmax_rows(const unsigned short* __restrict__ Pin,
                                                    unsigned short* __restrict__ P2) {
  const int row = blockIdx.x * 4 + (threadIdx.x >> 6);  // t*128 + h
  const int t = row >> 7, h = row & 127;
  const int lane = threadIdx.x & 63;
  const unsigned short* rp = Pin + (size_t)row * 512 + lane * 8;
  uint4 raw = *reinterpret_cast<const uint4*>(rp);
  unsigned int w[4] = {raw.x, raw.y, raw.z, raw.w};
  float f[8];
  float mx = -1e30f;
#pragma unroll
  for (int i = 0; i < 8; ++i) {
    f[i] = bf2f((unsigned short)((w[i >> 1] >> ((i & 1) * 16)) & 0xFFFF));
    mx = fmaxf(mx, f[i]);
  }
#pragma unroll
  for (int off = 32; off; off >>= 1) mx = fmaxf(mx, __shfl_xor(mx, off, 64));
  float s = 0.f;
#pragma unroll
  for (int i = 0; i < 8; ++i) { f[i] = __expf(f[i] - mx); s += f[i]; }
#pragma unroll
  for (int off = 32; off; off >>= 1) s += __shfl_xor(s, off, 64);
  const float inv = 1.0f / s;
  uint4 o;
  o.x = pack2(f[0] * inv, f[1] * inv);
  o.y = pack2(f[2] * inv, f[3] * inv);
  o.z = pack2(f[4] * inv, f[5] * inv);
  o.w = pack2(f[6] * inv, f[7] * inv);
  unsigned short* wp =
      P2 + (((size_t)t * 16 + (lane >> 2)) * 128 + h) * 32 + (lane & 3) * 8;
  *reinterpret_cast<uint4*>(wp) = o;
}

// ---------------- K4: attn_lat (128h x 128c tile) = P @ KVsel[:, :512] ----------------
// grid (512, 4): x = t. A-fragments straight from swizzled P2 (no LDS for A);
// St[key][c] double-buffered via DMA (issued post-barrier, overlaps MFMA);
// transpose St->Bs (stride-40, write/read at the 8-word/bank floor).
#define BSTRIDE 40
__global__ __launch_bounds__(256) void attn_gemm(const unsigned short* __restrict__ P2,
                                                 const unsigned short* __restrict__ kvb,
                                                 const int* __restrict__ topk,
                                                 unsigned short* __restrict__ alat) {
  const int t = blockIdx.x;
  const int tn = blockIdx.y * 128;  // c-dim tile
  __shared__ __align__(16) unsigned short St[2][32 * 128];
  __shared__ __align__(16) unsigned short Bs[128 * BSTRIDE];
  const int tid = threadIdx.x;
  const int lane = tid & 63, wave = tid >> 6;
  const int wm = (wave & 1) * 64, wn = (wave >> 1) * 64;
  const int l15 = lane & 15, quad = lane >> 4;
  const int key0 = tid >> 4;  // 0..15
  const int cs = tid & 15;    // uint4 slot in the 128-c row
  const int kgT = tid & 3;    // transpose: key-group 0..3
  const int cp = tid >> 2;    // transpose: c-pair 0..63
  const int* tkrow = topk + t * 512;
  // A-fragment base: P2[((t*16+ks)*128 + wm+i*16+l15)*32 + quad*8]
  const unsigned short* a_base =
      P2 + ((size_t)t * 16 * 128 + wm + l15) * 32 + quad * 8;
  floatx4 acc[4][4] = {};
  bf16x8 a_cur[4], a_nxt[4];
  // preload: St[0] DMA + A(ks=0) regs
  {
    const int i0 = tkrow[key0];
    const int i1 = tkrow[16 + key0];
    ldsdma16(kvb + (size_t)i0 * 576 + tn + cs * 8, &St[0][tid * 8]);
    ldsdma16(kvb + (size_t)i1 * 576 + tn + cs * 8, &St[0][2048 + tid * 8]);
#pragma unroll
    for (int i = 0; i < 4; ++i)
      a_cur[i] = *reinterpret_cast<const bf16x8*>(a_base + (size_t)i * 16 * 32);
  }
  __syncthreads();  // St[0] ready
  int cur = 0;
  for (int ks = 0; ks < 16; ++ks) {
    // transpose St[cur] -> Bs (c-pair b32 reads; b128 writes uniform 8/bank)
    unsigned int w[8];
#pragma unroll
    for (int i = 0; i < 8; ++i)
      w[i] = *reinterpret_cast<const unsigned int*>(
          &St[cur][(kgT * 8 + i) * 128 + cp * 2]);
    unsigned short r0[8], r1[8];
#pragma unroll
    for (int i = 0; i < 8; ++i) {
      r0[i] = (unsigned short)(w[i] & 0xFFFF);
      r1[i] = (unsigned short)(w[i] >> 16);
    }
    *reinterpret_cast<uint4*>(&Bs[(2 * cp) * BSTRIDE + kgT * 8]) =
        *reinterpret_cast<const uint4*>(r0);
    *reinterpret_cast<uint4*>(&Bs[(2 * cp + 1) * BSTRIDE + kgT * 8]) =
        *reinterpret_cast<const uint4*>(r1);
    __syncthreads();  // Bs ready
    if (ks < 15) {
      // issue next gather (latency overlaps MFMA, drained by end barrier)
      const int i0 = tkrow[(ks + 1) * 32 + key0];
      const int i1 = tkrow[(ks + 1) * 32 + 16 + key0];
      ldsdma16(kvb + (size_t)i0 * 576 + tn + cs * 8, &St[cur ^ 1][tid * 8]);
      ldsdma16(kvb + (size_t)i1 * 576 + tn + cs * 8, &St[cur ^ 1][2048 + tid * 8]);
#pragma unroll
      for (int i = 0; i < 4; ++i)
        a_nxt[i] = *reinterpret_cast<const bf16x8*>(
            a_base + ((size_t)(ks + 1) * 128 + i * 16) * 32);
    }
    bf16x8 bfr[4];
#pragma unroll
    for (int j = 0; j < 4; ++j)
      bfr[j] = *reinterpret_cast<const bf16x8*>(
          &Bs[(wn + j * 16 + l15) * BSTRIDE + quad * 8]);
#pragma unroll
    for (int i = 0; i < 4; ++i)
#pragma unroll
      for (int j = 0; j < 4; ++j)
        acc[i][j] =
            __builtin_amdgcn_mfma_f32_16x16x32_bf16(a_cur[i], bfr[j], acc[i][j], 0, 0, 0);
    __syncthreads();  // Bs consumed; St[cur^1] DMA drained
#pragma unroll
    for (int i = 0; i < 4; ++i) a_cur[i] = a_nxt[i];
    cur ^= 1;
  }
  // write attn_lat in (H, T, 512) layout for K5's contiguous A reads
#pragma unroll
  for (int i = 0; i < 4; ++i) {
    const int row = wm + i * 16 + quad * 4;  // head
#pragma unroll
    for (int j = 0; j < 4; ++j) {
      const int col = tn + wn + j * 16 + l15;  // c
#pragma unroll
      for (int r = 0; r < 4; ++r)
        alat[((size_t)(row + r) * 512 + t) * 512 + col] = f2bf(acc[i][j][r]);
    }
  }
}

// ---------------- K5: out (128t x 128v tile) = attn_lat[h] @ v_b[h]^T ----------------
// grid (128, 4): x = h so the 4 token-tile blocks sharing B[h] share an XCD L2.
__global__ __launch_bounds__(256) void out_gemm(const unsigned short* __restrict__ alat,
                                                const float* __restrict__ vb,
                                                float* __restrict__ out) {
  const int h = blockIdx.x;
  const int tm = blockIdx.y * 128;  // token tile
  __shared__ __align__(16) unsigned short As[128 * 32];
  __shared__ __align__(16) unsigned short Bs[128 * 32];
  const int tid = threadIdx.x;
  const int lane = tid & 63, wave = tid >> 6;
  const int wm = (wave & 1) * 64, wn = (wave >> 1) * 64;
  const int l15 = lane & 15, quad = lane >> 4;
  const int r0 = tid >> 2, cg = tid & 3;
  const unsigned short* a0 = alat + ((size_t)h * 512 + tm + r0) * 512 + cg * 8;
  const unsigned short* a1 = a0 + (size_t)64 * 512;
  const float* b0 = vb + ((size_t)h * 128 + r0) * 512 + cg * 8;
  const float* b1 = b0 + (size_t)64 * 512;
  floatx4 acc[4][4] = {};
  for (int ks = 0; ks < 16; ++ks) {  // contraction 512 = 16*32
    ldsdma16(a0 + ks * 32, &As[tid * 8]);
    ldsdma16(a1 + ks * 32, &As[2048 + tid * 8]);
    stage8_f32(b0 + ks * 32, &Bs[tid * 8]);
    stage8_f32(b1 + ks * 32, &Bs[2048 + tid * 8]);
    __syncthreads();
    mfma_4x4(As, Bs, wm, wn, l15, quad, acc);
    __syncthreads();
  }
#pragma unroll
  for (int i = 0; i < 4; ++i) {
    const int row = wm + i * 16 + quad * 4;  // token-local
#pragma unroll
    for (int j = 0; j < 4; ++j) {
      const int col = wn + j * 16 + l15;  // v
#pragma unroll
      for (int r = 0; r < 4; ++r) {
        const int t = tm + row + r;
        out[((size_t)t * 128 + h) * 128 + col] = acc[i][j][r];
      }
    }
  }
}

extern "C" void kernel_launch(void* const* d_in, const int* in_sizes, int n_in,
                              void* d_out, int out_size, void* d_ws, size_t ws_size,
                              hipStream_t stream) {
  const float* q = (const float*)d_in[0];         // (512,128,192)
  const float* kv = (const float*)d_in[1];        // (8192,576)
  const int* topk = (const int*)d_in[2];          // (512,512)
  const float* kb = (const float*)d_in[3];        // (128,512,128)
  const float* vb = (const float*)d_in[4];        // (128,128,512)
  float* out = (float*)d_out;                     // (512,128,128)

  char* ws = (char*)d_ws;
  unsigned short* kvb = (unsigned short*)ws;                       // 9,437,184 B
  unsigned short* qc = (unsigned short*)(ws + 9437184);            // 75,497,472 B
  unsigned short* P = (unsigned short*)(ws + 9437184 + 75497472);  // 67,108,864 B
  // lifetime reuse (no growth, 152 MB total):
  unsigned short* P2 = qc;    // qc dead after scores_gemm; softmax writes here
  unsigned short* alat = P;   // P dead after softmax; attn writes here

  kv_convert<<<dim3(4608), dim3(256), 0, stream>>>(kv, kvb);
  rope_copy<<<dim3(16384), dim3(256), 0, stream>>>(q, qc);
  qlat_gemm<<<dim3(128, 16), dim3(256), 0, stream>>>(q, kb, qc);
  scores_gemm<<<dim3(512, 4), dim3(256), 0, stream>>>(qc, kvb, topk, P);
  softmax_rows<<<dim3(16384), dim3(256), 0, stream>>>(P, P2);
  attn_gemm<<<dim3(512, 4), dim3(256), 0, stream>>>(P2, kvb, topk, alat);
  out_gemm<<<dim3(128, 4), dim3(256), 0, stream>>>(alat, vb, out);
}